// Round 9
// baseline (114.995 us; speedup 1.0000x reference)
//
#include <hip/hip_runtime.h>

// VQ-VAE vector quantization via bf16-split MFMA (x=xh+xl, c=ch+cl; score =
// xh.ch + xh.cl + xl.ch - 0.5||c||^2, err ~2^-18 relative).
// Round 9: de-contend L2 hot lines (theory: all 1024 blocks reading the SAME
// 16KB chunk simultaneously serializes at L2). Changes vs round 8:
//   1) chunk-order stagger per block (argmax is visit-order independent)
//   2) packed codebook + norms replicated nrep x (host picks nrep from ws_size,
//      up to 8); rep = (blk>>3)&(nrep-1) so blocks WITHIN an XCD use
//      different copies (L2s are per-XCD; consecutive blk round-robin XCDs)
//   3) qidx stored as u16 (ci < 1024) to shrink ws footprint
// ws layout (floats):
//   [0..31]          loss partials
//   [1024..33791]    hist partials 32 x 1024
//   [34816..100351]  qidx as ushort[131072]
//   [100352..100352+nrep*1024)  nhn replicas
//   [110592..110592+nrep*65536) packed replicas: 16 chunks x 4096 floats
//                    (16KB): [16 granules][64 codes][16B]; g<8: hi, g>=8: lo

typedef __attribute__((ext_vector_type(8))) short short8;
typedef __attribute__((ext_vector_type(16))) float f32x16;

#define LOSS_OFF 0
#define PART_OFF 1024
#define QIDX_OFF 34816
#define NHN_OFF 100352
#define PACKED_OFF 110592
#define NPART 32

#define GLL16(gsrc, ldst)                                                      \
  __builtin_amdgcn_global_load_lds(                                            \
      (const __attribute__((address_space(1))) void*)(gsrc),                   \
      (__attribute__((address_space(3))) void*)(ldst), 16, 0, 0)

__device__ __forceinline__ unsigned short bf16_rne(float v, float& rest) {
  const unsigned u = __float_as_uint(v);
  const unsigned r = u + 0x7fffu + ((u >> 16) & 1u);
  const unsigned short h = (unsigned short)(r >> 16);
  rest = v - __uint_as_float((unsigned)h << 16);
  return h;
}

__global__ void vq_pack(const float* __restrict__ cb0, const float* __restrict__ cb1,
                        float* __restrict__ ws, int nrep) {
  const int c = blockIdx.x * 256 + threadIdx.x;  // 0..1023
  if (c < NPART) ws[LOSS_OFF + c] = 0.0f;
#pragma unroll
  for (int p = 0; p < NPART; ++p) ws[PART_OFF + p * 1024 + c] = 0.0f;
  const float* row = (c < 512) ? (cb0 + (size_t)c * 64) : (cb1 + (size_t)(c - 512) * 64);
  float v[64];
  float nrm = 0.f;
#pragma unroll
  for (int d = 0; d < 64; d += 4) {
    const float4 f = *(const float4*)(row + d);
    v[d] = f.x; v[d + 1] = f.y; v[d + 2] = f.z; v[d + 3] = f.w;
    nrm += f.x * f.x + f.y * f.y + f.z * f.z + f.w * f.w;
  }
  unsigned short hi[64], lo[64];
#pragma unroll
  for (int d = 0; d < 64; ++d) {
    float rest, dump;
    hi[d] = bf16_rne(v[d], rest);
    lo[d] = bf16_rne(rest, dump);
  }
  short8 gr[16];
#pragma unroll
  for (int g = 0; g < 16; ++g)
#pragma unroll
    for (int e = 0; e < 8; ++e)
      gr[g][e] = (short)((g < 8) ? hi[g * 8 + e] : lo[(g - 8) * 8 + e]);
  for (int r = 0; r < nrep; ++r) {
    ws[NHN_OFF + r * 1024 + c] = -0.5f * nrm;
    float* base = ws + PACKED_OFF + (size_t)r * 65536 + (size_t)(c >> 6) * 4096 + (c & 63) * 4;
#pragma unroll
    for (int g = 0; g < 16; ++g) *(short8*)(base + g * 256) = gr[g];
  }
}

__global__ __launch_bounds__(256, 4) void vq_dist(
    const float* __restrict__ xin, const int* __restrict__ idxp,
    float* __restrict__ ws, int nrep) {
  __shared__ char ring[32768];  // 2 x 16KB B double-buffer (only LDS use)
  const int tid = threadIdx.x;
  const int w = tid >> 6;      // wave 0..3, owns q rows w*32..+31
  const int l = tid & 63;
  const int half = l >> 5;
  const int col = l & 31;
  const int blk = blockIdx.x;  // 1024 blocks x 128 q
  const int bb = blk >> 5;
  const int hw0 = (blk & 31) << 7;
  const int nch = (*idxp == 0) ? 8 : 16;
  const int rep = (blk >> 3) & (nrep - 1);   // spread WITHIN an XCD
  const int start = ((blk >> 6) * 5) & (nch - 1);  // chunk-order stagger
  const float* nhn = ws + NHN_OFF + (size_t)rep * 1024;
  const char* pk = (const char*)(ws + PACKED_OFF + (size_t)rep * 65536);

  // ---- x: direct global->reg (no LDS), per instr two 128B segments
  short8 xh[4], xl[4];
  float xx;
  {
    float vv[4][8];
    const float* xb = xin + ((size_t)(bb * 64 + half * 8)) * 4096 + hw0 + w * 32 + col;
#pragma unroll
    for (int kf = 0; kf < 4; ++kf)
#pragma unroll
      for (int j = 0; j < 8; ++j)
        vv[kf][j] = xb[((size_t)(kf * 16 + j)) * 4096];
    float s = 0.f;
#pragma unroll
    for (int kf = 0; kf < 4; ++kf)
#pragma unroll
      for (int j = 0; j < 8; ++j) {
        const float v = vv[kf][j];
        float rest, dump;
        xh[kf][j] = (short)bf16_rne(v, rest);
        xl[kf][j] = (short)bf16_rne(rest, dump);
        s += v * v;
      }
    s += __shfl_xor(s, 32);  // lanes l, l^32: same q, complementary dims
    xx = s;
  }
  asm volatile("s_waitcnt vmcnt(0)" ::: "memory");  // x loads retired

  // best[r]: score with low 5 mantissa bits = (31 - (ch*2+n)); fmax prefers
  // smaller code index on near-ties (visit-order independent).
  float best[16];
#pragma unroll
  for (int r = 0; r < 16; ++r) best[r] = -3.4e38f;

  auto stage = [&](int ch, int buf) {
    const char* src = pk + (size_t)ch * 16384 + w * 1024 + l * 16;
    char* dst = ring + buf * 16384 + w * 1024;
#pragma unroll
    for (int i = 0; i < 4; ++i) GLL16(src + i * 4096, dst + i * 4096);
  };

  stage(start, 0);
  for (int i = 0; i < nch; ++i) {
    const int ch = (start + i) & (nch - 1);
    __builtin_amdgcn_s_barrier();  // A: all waves done reading buf[(i+1)&1]
    if (i + 1 < nch) {
      stage((start + i + 1) & (nch - 1), (i + 1) & 1);
      asm volatile("s_waitcnt vmcnt(4)" ::: "memory");  // own slice of ch done
    } else {
      asm volatile("s_waitcnt vmcnt(0)" ::: "memory");
    }
    __builtin_amdgcn_s_barrier();  // B: chunk ch resident for all waves
    __builtin_amdgcn_sched_barrier(0);
    const char* bufp = ring + (i & 1) * 16384;
    const int cb = col * 16;
    const float nh0 = nhn[ch * 64 + col];
    const float nh1 = nhn[ch * 64 + 32 + col];
    f32x16 a0, a1;
#pragma unroll
    for (int r = 0; r < 16; ++r) { a0[r] = nh0; a1[r] = nh1; }
    __builtin_amdgcn_s_setprio(1);
#pragma unroll
    for (int kf = 0; kf < 4; ++kf) {
      const char* ph = bufp + (2 * kf + half) * 1024 + cb;
      const char* pl = bufp + (8 + 2 * kf + half) * 1024 + cb;
      const short8 bh0 = *(const short8*)(ph);
      const short8 bh1 = *(const short8*)(ph + 512);
      const short8 bl0 = *(const short8*)(pl);
      const short8 bl1 = *(const short8*)(pl + 512);
      a0 = __builtin_amdgcn_mfma_f32_32x32x16_bf16(xh[kf], bh0, a0, 0, 0, 0);
      a1 = __builtin_amdgcn_mfma_f32_32x32x16_bf16(xh[kf], bh1, a1, 0, 0, 0);
      a0 = __builtin_amdgcn_mfma_f32_32x32x16_bf16(xh[kf], bl0, a0, 0, 0, 0);
      a1 = __builtin_amdgcn_mfma_f32_32x32x16_bf16(xh[kf], bl1, a1, 0, 0, 0);
      a0 = __builtin_amdgcn_mfma_f32_32x32x16_bf16(xl[kf], bh0, a0, 0, 0, 0);
      a1 = __builtin_amdgcn_mfma_f32_32x32x16_bf16(xl[kf], bh1, a1, 0, 0, 0);
    }
    __builtin_amdgcn_s_setprio(0);
    const unsigned sid0 = (unsigned)(31 - 2 * ch);
    const unsigned sid1 = (unsigned)(30 - 2 * ch);
#pragma unroll
    for (int r = 0; r < 16; ++r) {
      const unsigned p0 = (__float_as_uint(a0[r]) & 0xFFFFFFE0u) | sid0;
      const unsigned p1 = (__float_as_uint(a1[r]) & 0xFFFFFFE0u) | sid1;
      best[r] = fmaxf(best[r], fmaxf(__uint_as_float(p0), __uint_as_float(p1)));
    }
  }

  // ---- cross-lane argmax reduce (within 32-lane half), first-index ties
  unsigned short* qidx = (unsigned short*)(ws + QIDX_OFF);
  float ls = 0.f;
#pragma unroll
  for (int r = 0; r < 16; ++r) {
    float v = best[r];
    int idx = (int)(31u - (__float_as_uint(v) & 31u)) * 32 + col;
#pragma unroll
    for (int mk = 1; mk < 32; mk <<= 1) {
      const float ov = __shfl_xor(v, mk);
      const int oi = __shfl_xor(idx, mk);
      if (ov > v || (ov == v && oi < idx)) { v = ov; idx = oi; }
    }
    const int row = (r & 3) + 8 * (r >> 2) + 4 * half;  // C layout row
    if (col == row) {
      const float vc = __uint_as_float(__float_as_uint(v) & 0xFFFFFFE0u);
      ls += xx - 2.0f * vc;  // ||x||^2 - 2(x.c* - 0.5||c*||^2) = ||x-c*||^2
      qidx[blk * 128 + w * 32 + row] = (unsigned short)idx;
    }
  }
#pragma unroll
  for (int mk = 1; mk < 64; mk <<= 1) ls += __shfl_xor(ls, mk);
  if (l == 0) atomicAdd(&ws[LOSS_OFF + (blk & (NPART - 1))], ls);
}

__global__ __launch_bounds__(256) void vq_out(
    const float* __restrict__ cb0, const float* __restrict__ cb1,
    float* __restrict__ out, float* __restrict__ ws) {
  const int tid = threadIdx.x;
  const int blk = blockIdx.x;  // 512 blocks x 256 q
  const int bb = blk >> 4;
  const int hw0 = (blk & 15) << 8;
  const int q = bb * 4096 + hw0 + tid;
  const int ci = (int)((const unsigned short*)(ws + QIDX_OFF))[q];
  atomicAdd(ws + PART_OFF + (size_t)(blk & (NPART - 1)) * 1024 + ci, 1.0f);
  const float* crow = (ci < 512) ? (cb0 + (size_t)ci * 64) : (cb1 + (size_t)(ci - 512) * 64);
  float* ob = out + (((size_t)(bb * 64)) << 12) + hw0 + tid;
#pragma unroll
  for (int d4 = 0; d4 < 16; ++d4) {
    const float4 f = *(const float4*)(crow + d4 * 4);
    ob[((size_t)(d4 * 4 + 0)) << 12] = f.x;
    ob[((size_t)(d4 * 4 + 1)) << 12] = f.y;
    ob[((size_t)(d4 * 4 + 2)) << 12] = f.z;
    ob[((size_t)(d4 * 4 + 3)) << 12] = f.w;
  }
}

__global__ void vq_final(const float* __restrict__ ws, float* __restrict__ out) {
  __shared__ float sred[256];
  const int t = threadIdx.x;
  float h = 0.f;
#pragma unroll
  for (int i = t; i < 1024; i += 256) {
    float s = 0.f;
#pragma unroll
    for (int p = 0; p < NPART; ++p) s += ws[PART_OFF + p * 1024 + i];
    const float avg = s * (1.0f / 131072.0f);
    h += avg * logf(avg + 1e-10f);
  }
  sred[t] = h;
  __syncthreads();
  for (int s2 = 128; s2 > 0; s2 >>= 1) {
    if (t < s2) sred[t] += sred[t + s2];
    __syncthreads();
  }
  if (t == 0) {
    float lsum = 0.f;
#pragma unroll
    for (int p = 0; p < NPART; ++p) lsum += ws[LOSS_OFF + p];
    out[8388608] = 1.25f * lsum * (1.0f / 8388608.0f);
    out[8388609] = expf(-sred[0]);
  }
}

extern "C" void kernel_launch(void* const* d_in, const int* in_sizes, int n_in,
                              void* d_out, int out_size, void* d_ws, size_t ws_size,
                              hipStream_t stream) {
  (void)in_sizes; (void)n_in; (void)out_size;
  const float* xin = (const float*)d_in[0];
  const float* cb0 = (const float*)d_in[1];
  const float* cb1 = (const float*)d_in[2];
  const int* idxp = (const int*)d_in[3];
  float* out = (float*)d_out;
  float* ws = (float*)d_ws;

  int nrep = 1;
  if (ws_size >= (size_t)(PACKED_OFF + 8 * 65536) * 4) nrep = 8;
  else if (ws_size >= (size_t)(PACKED_OFF + 4 * 65536) * 4) nrep = 4;
  else if (ws_size >= (size_t)(PACKED_OFF + 2 * 65536) * 4) nrep = 2;

  vq_pack<<<4, 256, 0, stream>>>(cb0, cb1, ws, nrep);
  vq_dist<<<1024, 256, 0, stream>>>(xin, idxp, ws, nrep);
  vq_out<<<512, 256, 0, stream>>>(cb0, cb1, out, ws);
  vq_final<<<1, 256, 0, stream>>>(ws, out);
}

// Round 10
// 103.838 us; speedup vs baseline: 1.1074x; 1.1074x over previous
//
#include <hip/hip_runtime.h>

// VQ-VAE vector quantization via bf16-split MFMA (x=xh+xl, c=ch+cl; score =
// xh.ch + xh.cl + xl.ch - 0.5||c||^2, err ~2^-18 relative).
// Round 10: deep-pipelined K-loop (T3+T4 done right). Ring 4x16KB, prefetch
// depth 3 chunks, ONE raw s_barrier per chunk, vmcnt(4/2/0) counted so the
// wait targets a chunk issued 3 windows earlier (pre-satisfied in steady
// state). 8-wave blocks (256 q), grid 512 = 2 blocks/CU = 16 waves/CU.
// Compute interleaved in 4 sub-phases {4 ds_read_b128; lgkmcnt; 6 MFMA}.
// ws layout (floats):
//   [0..31]         loss partials
//   [1024..2047]    nhn = -0.5||c||^2
//   [2048..34815]   hist partials 32 x 1024
//   [34816..100351] packed codes: 16 chunks x 4096 floats (16KB):
//                   [16 granules][64 codes][16B]; g<8: hi dims 8g.., g>=8: lo
//   [102400..167935] qidx as ushort[131072]

typedef __attribute__((ext_vector_type(8))) short short8;
typedef __attribute__((ext_vector_type(16))) float f32x16;

#define LOSS_OFF 0
#define NHN_OFF 1024
#define PART_OFF 2048
#define PACKED_OFF 34816
#define QIDX_OFF 102400
#define NPART 32

#define GLL16(gsrc, ldst)                                                      \
  __builtin_amdgcn_global_load_lds(                                            \
      (const __attribute__((address_space(1))) void*)(gsrc),                   \
      (__attribute__((address_space(3))) void*)(ldst), 16, 0, 0)

__device__ __forceinline__ unsigned short bf16_rne(float v, float& rest) {
  const unsigned u = __float_as_uint(v);
  const unsigned r = u + 0x7fffu + ((u >> 16) & 1u);
  const unsigned short h = (unsigned short)(r >> 16);
  rest = v - __uint_as_float((unsigned)h << 16);
  return h;
}

__global__ void vq_pack(const float* __restrict__ cb0, const float* __restrict__ cb1,
                        float* __restrict__ ws) {
  const int c = blockIdx.x * 256 + threadIdx.x;  // 0..1023
  if (c < NPART) ws[LOSS_OFF + c] = 0.0f;
#pragma unroll
  for (int p = 0; p < NPART; ++p) ws[PART_OFF + p * 1024 + c] = 0.0f;
  const float* row = (c < 512) ? (cb0 + (size_t)c * 64) : (cb1 + (size_t)(c - 512) * 64);
  float v[64];
  float nrm = 0.f;
#pragma unroll
  for (int d = 0; d < 64; d += 4) {
    const float4 f = *(const float4*)(row + d);
    v[d] = f.x; v[d + 1] = f.y; v[d + 2] = f.z; v[d + 3] = f.w;
    nrm += f.x * f.x + f.y * f.y + f.z * f.z + f.w * f.w;
  }
  ws[NHN_OFF + c] = -0.5f * nrm;
  unsigned short hi[64], lo[64];
#pragma unroll
  for (int d = 0; d < 64; ++d) {
    float rest, dump;
    hi[d] = bf16_rne(v[d], rest);
    lo[d] = bf16_rne(rest, dump);
  }
  float* base = ws + PACKED_OFF + (size_t)(c >> 6) * 4096 + (c & 63) * 4;
#pragma unroll
  for (int g = 0; g < 16; ++g) {
    short8 gr;
#pragma unroll
    for (int e = 0; e < 8; ++e)
      gr[e] = (short)((g < 8) ? hi[g * 8 + e] : lo[(g - 8) * 8 + e]);
    *(short8*)(base + g * 256) = gr;
  }
}

__global__ __launch_bounds__(512, 4) void vq_dist(
    const float* __restrict__ xin, const int* __restrict__ idxp,
    float* __restrict__ ws) {
  __shared__ char ring[65536];  // 4 x 16KB ring (only LDS use)
  const int tid = threadIdx.x;
  const int w = tid >> 6;      // wave 0..7, owns q rows w*32..+31
  const int l = tid & 63;
  const int half = l >> 5;
  const int col = l & 31;
  const int blk = blockIdx.x;  // 512 blocks x 256 q
  const int bb = blk >> 4;
  const int hw0 = (blk & 15) << 8;
  const int nch = (*idxp == 0) ? 8 : 16;
  const float* nhn = ws + NHN_OFF;
  const char* pk = (const char*)(ws + PACKED_OFF);

  // ---- x: direct global->reg (no LDS), per instr two 128B segments
  short8 xh[4], xl[4];
  float xx;
  {
    float vv[4][8];
    const float* xb = xin + ((size_t)(bb * 64 + half * 8)) * 4096 + hw0 + w * 32 + col;
#pragma unroll
    for (int kf = 0; kf < 4; ++kf)
#pragma unroll
      for (int j = 0; j < 8; ++j)
        vv[kf][j] = xb[((size_t)(kf * 16 + j)) * 4096];
    float s = 0.f;
#pragma unroll
    for (int kf = 0; kf < 4; ++kf)
#pragma unroll
      for (int j = 0; j < 8; ++j) {
        const float v = vv[kf][j];
        float rest, dump;
        xh[kf][j] = (short)bf16_rne(v, rest);
        xl[kf][j] = (short)bf16_rne(rest, dump);
        s += v * v;
      }
    s += __shfl_xor(s, 32);  // lanes l, l^32: same q, complementary dims
    xx = s;
  }
  asm volatile("s_waitcnt vmcnt(0)" ::: "memory");  // x retired: clean count

  // best[r]: score with low 5 mantissa bits = (31 - (ch*2+n)); fmax prefers
  // smaller code index on near-ties. <=2^-18 perturbation.
  float best[16];
#pragma unroll
  for (int r = 0; r < 16; ++r) best[r] = -3.4e38f;

  // stage chunk ch: 16KB over 8 waves -> 2 x 1KB GLL per wave
  auto stage = [&](int ch, int buf) {
    const char* src = pk + (size_t)ch * 16384 + w * 2048 + l * 16;
    char* dst = ring + buf * 16384 + w * 2048;
    GLL16(src, dst);
    GLL16(src + 1024, dst + 1024);
  };

  stage(0, 0);
  stage(1, 1);
  stage(2, 2);  // 6 outstanding per wave
  for (int i = 0; i < nch; ++i) {
    // wait for chunk i (its 2 GLLs are the oldest in flight)
    if (i < nch - 2) {
      asm volatile("s_waitcnt vmcnt(4)" ::: "memory");
    } else if (i == nch - 2) {
      asm volatile("s_waitcnt vmcnt(2)" ::: "memory");
    } else {
      asm volatile("s_waitcnt vmcnt(0)" ::: "memory");
    }
    __builtin_amdgcn_s_barrier();  // chunk i resident for ALL waves; i-1 consumed
    if (i + 3 < nch) stage(i + 3, (i + 3) & 3);  // overwrites buf[(i-1)&3]: safe
    const char* bufp = ring + (i & 3) * 16384;
    const int cb = col * 16;
    const float nh0 = nhn[i * 64 + col];
    const float nh1 = nhn[i * 64 + 32 + col];
    f32x16 a0, a1;
#pragma unroll
    for (int r = 0; r < 16; ++r) { a0[r] = nh0; a1[r] = nh1; }
#pragma unroll
    for (int kf = 0; kf < 4; ++kf) {  // 4 sub-phases: 4 ds_read + 6 MFMA each
      const char* ph = bufp + (2 * kf + half) * 1024 + cb;
      const char* pl = bufp + (8 + 2 * kf + half) * 1024 + cb;
      const short8 bh0 = *(const short8*)(ph);
      const short8 bh1 = *(const short8*)(ph + 512);
      const short8 bl0 = *(const short8*)(pl);
      const short8 bl1 = *(const short8*)(pl + 512);
      asm volatile("s_waitcnt lgkmcnt(0)" ::: "memory");
      __builtin_amdgcn_sched_barrier(0);
      __builtin_amdgcn_s_setprio(1);
      a0 = __builtin_amdgcn_mfma_f32_32x32x16_bf16(xh[kf], bh0, a0, 0, 0, 0);
      a1 = __builtin_amdgcn_mfma_f32_32x32x16_bf16(xh[kf], bh1, a1, 0, 0, 0);
      a0 = __builtin_amdgcn_mfma_f32_32x32x16_bf16(xh[kf], bl0, a0, 0, 0, 0);
      a1 = __builtin_amdgcn_mfma_f32_32x32x16_bf16(xh[kf], bl1, a1, 0, 0, 0);
      a0 = __builtin_amdgcn_mfma_f32_32x32x16_bf16(xl[kf], bh0, a0, 0, 0, 0);
      a1 = __builtin_amdgcn_mfma_f32_32x32x16_bf16(xl[kf], bh1, a1, 0, 0, 0);
      __builtin_amdgcn_s_setprio(0);
    }
    const unsigned sid0 = (unsigned)(31 - 2 * i);
    const unsigned sid1 = (unsigned)(30 - 2 * i);
#pragma unroll
    for (int r = 0; r < 16; ++r) {
      const unsigned p0 = (__float_as_uint(a0[r]) & 0xFFFFFFE0u) | sid0;
      const unsigned p1 = (__float_as_uint(a1[r]) & 0xFFFFFFE0u) | sid1;
      best[r] = fmaxf(best[r], fmaxf(__uint_as_float(p0), __uint_as_float(p1)));
    }
  }

  // ---- cross-lane argmax reduce (within 32-lane half), first-index ties
  unsigned short* qidx = (unsigned short*)(ws + QIDX_OFF);
  float ls = 0.f;
#pragma unroll
  for (int r = 0; r < 16; ++r) {
    float v = best[r];
    int idx = (int)(31u - (__float_as_uint(v) & 31u)) * 32 + col;
#pragma unroll
    for (int mk = 1; mk < 32; mk <<= 1) {
      const float ov = __shfl_xor(v, mk);
      const int oi = __shfl_xor(idx, mk);
      if (ov > v || (ov == v && oi < idx)) { v = ov; idx = oi; }
    }
    const int row = (r & 3) + 8 * (r >> 2) + 4 * half;  // C layout row
    if (col == row) {
      const float vc = __uint_as_float(__float_as_uint(v) & 0xFFFFFFE0u);
      ls += xx - 2.0f * vc;  // ||x||^2 - 2(x.c* - 0.5||c*||^2) = ||x-c*||^2
      qidx[blk * 256 + w * 32 + row] = (unsigned short)idx;
    }
  }
#pragma unroll
  for (int mk = 1; mk < 64; mk <<= 1) ls += __shfl_xor(ls, mk);
  if (l == 0) atomicAdd(&ws[LOSS_OFF + (blk & (NPART - 1))], ls);
}

__global__ __launch_bounds__(256) void vq_out(
    const float* __restrict__ cb0, const float* __restrict__ cb1,
    float* __restrict__ out, float* __restrict__ ws) {
  const int tid = threadIdx.x;
  const int blk = blockIdx.x;  // 512 blocks x 256 q
  const int bb = blk >> 4;
  const int hw0 = (blk & 15) << 8;
  const int q = bb * 4096 + hw0 + tid;
  const int ci = (int)((const unsigned short*)(ws + QIDX_OFF))[q];
  atomicAdd(ws + PART_OFF + (size_t)(blk & (NPART - 1)) * 1024 + ci, 1.0f);
  const float* crow = (ci < 512) ? (cb0 + (size_t)ci * 64) : (cb1 + (size_t)(ci - 512) * 64);
  float* ob = out + (((size_t)(bb * 64)) << 12) + hw0 + tid;
#pragma unroll
  for (int d4 = 0; d4 < 16; ++d4) {
    const float4 f = *(const float4*)(crow + d4 * 4);
    ob[((size_t)(d4 * 4 + 0)) << 12] = f.x;
    ob[((size_t)(d4 * 4 + 1)) << 12] = f.y;
    ob[((size_t)(d4 * 4 + 2)) << 12] = f.z;
    ob[((size_t)(d4 * 4 + 3)) << 12] = f.w;
  }
}

__global__ void vq_final(const float* __restrict__ ws, float* __restrict__ out) {
  __shared__ float sred[256];
  const int t = threadIdx.x;
  float h = 0.f;
#pragma unroll
  for (int i = t; i < 1024; i += 256) {
    float s = 0.f;
#pragma unroll
    for (int p = 0; p < NPART; ++p) s += ws[PART_OFF + p * 1024 + i];
    const float avg = s * (1.0f / 131072.0f);
    h += avg * logf(avg + 1e-10f);
  }
  sred[t] = h;
  __syncthreads();
  for (int s2 = 128; s2 > 0; s2 >>= 1) {
    if (t < s2) sred[t] += sred[t + s2];
    __syncthreads();
  }
  if (t == 0) {
    float lsum = 0.f;
#pragma unroll
    for (int p = 0; p < NPART; ++p) lsum += ws[LOSS_OFF + p];
    out[8388608] = 1.25f * lsum * (1.0f / 8388608.0f);
    out[8388609] = expf(-sred[0]);
  }
}

extern "C" void kernel_launch(void* const* d_in, const int* in_sizes, int n_in,
                              void* d_out, int out_size, void* d_ws, size_t ws_size,
                              hipStream_t stream) {
  (void)in_sizes; (void)n_in; (void)out_size; (void)ws_size;
  const float* xin = (const float*)d_in[0];
  const float* cb0 = (const float*)d_in[1];
  const float* cb1 = (const float*)d_in[2];
  const int* idxp = (const int*)d_in[3];
  float* out = (float*)d_out;
  float* ws = (float*)d_ws;

  vq_pack<<<4, 256, 0, stream>>>(cb0, cb1, ws);
  vq_dist<<<512, 512, 0, stream>>>(xin, idxp, ws);
  vq_out<<<512, 256, 0, stream>>>(cb0, cb1, out, ws);
  vq_final<<<1, 256, 0, stream>>>(ws, out);
}

// Round 11
// 101.528 us; speedup vs baseline: 1.1326x; 1.0228x over previous
//
#include <hip/hip_runtime.h>

// VQ-VAE vector quantization via bf16-split MFMA (x=xh+xl, c=ch+cl; score =
// xh.ch + xh.cl + xl.ch - 0.5||c||^2, err ~2^-18 relative).
// Round 11: round 10 ring-4 deep pipeline + ONE fix: nhn moved to LDS.
// Theory: the in-loop global loads of nhn forced a compiler vmcnt drain of
// ALL outstanding chunk DMAs every iteration (vmcnt waits are oldest-first),
// so rounds 2-10 were never actually pipelined. With nhn in LDS the K-loop
// has zero non-GLL VMEM and vmcnt(4) is pre-satisfied in steady state.
// ws layout (floats):
//   [0..31]         loss partials
//   [1024..2047]    nhn = -0.5||c||^2
//   [2048..34815]   hist partials 32 x 1024
//   [34816..100351] packed codes: 16 chunks x 4096 floats (16KB):
//                   [16 granules][64 codes][16B]; g<8: hi dims 8g.., g>=8: lo
//   [102400..167935] qidx as ushort[131072]

typedef __attribute__((ext_vector_type(8))) short short8;
typedef __attribute__((ext_vector_type(16))) float f32x16;

#define LOSS_OFF 0
#define NHN_OFF 1024
#define PART_OFF 2048
#define PACKED_OFF 34816
#define QIDX_OFF 102400
#define NPART 32

#define GLL16(gsrc, ldst)                                                      \
  __builtin_amdgcn_global_load_lds(                                            \
      (const __attribute__((address_space(1))) void*)(gsrc),                   \
      (__attribute__((address_space(3))) void*)(ldst), 16, 0, 0)

__device__ __forceinline__ unsigned short bf16_rne(float v, float& rest) {
  const unsigned u = __float_as_uint(v);
  const unsigned r = u + 0x7fffu + ((u >> 16) & 1u);
  const unsigned short h = (unsigned short)(r >> 16);
  rest = v - __uint_as_float((unsigned)h << 16);
  return h;
}

__global__ void vq_pack(const float* __restrict__ cb0, const float* __restrict__ cb1,
                        float* __restrict__ ws) {
  const int c = blockIdx.x * 256 + threadIdx.x;  // 0..1023
  if (c < NPART) ws[LOSS_OFF + c] = 0.0f;
#pragma unroll
  for (int p = 0; p < NPART; ++p) ws[PART_OFF + p * 1024 + c] = 0.0f;
  const float* row = (c < 512) ? (cb0 + (size_t)c * 64) : (cb1 + (size_t)(c - 512) * 64);
  float v[64];
  float nrm = 0.f;
#pragma unroll
  for (int d = 0; d < 64; d += 4) {
    const float4 f = *(const float4*)(row + d);
    v[d] = f.x; v[d + 1] = f.y; v[d + 2] = f.z; v[d + 3] = f.w;
    nrm += f.x * f.x + f.y * f.y + f.z * f.z + f.w * f.w;
  }
  ws[NHN_OFF + c] = -0.5f * nrm;
  unsigned short hi[64], lo[64];
#pragma unroll
  for (int d = 0; d < 64; ++d) {
    float rest, dump;
    hi[d] = bf16_rne(v[d], rest);
    lo[d] = bf16_rne(rest, dump);
  }
  float* base = ws + PACKED_OFF + (size_t)(c >> 6) * 4096 + (c & 63) * 4;
#pragma unroll
  for (int g = 0; g < 16; ++g) {
    short8 gr;
#pragma unroll
    for (int e = 0; e < 8; ++e)
      gr[e] = (short)((g < 8) ? hi[g * 8 + e] : lo[(g - 8) * 8 + e]);
    *(short8*)(base + g * 256) = gr;
  }
}

__global__ __launch_bounds__(512, 4) void vq_dist(
    const float* __restrict__ xin, const int* __restrict__ idxp,
    float* __restrict__ ws) {
  __shared__ char smem[69632];  // 4 x 16KB ring + 4KB nhn
  char* ring = smem;
  float* nhl = (float*)(smem + 65536);
  const int tid = threadIdx.x;
  const int w = tid >> 6;      // wave 0..7, owns q rows w*32..+31
  const int l = tid & 63;
  const int half = l >> 5;
  const int col = l & 31;
  const int blk = blockIdx.x;  // 512 blocks x 256 q
  const int bb = blk >> 4;
  const int hw0 = (blk & 15) << 8;
  const int nch = (*idxp == 0) ? 8 : 16;
  const char* pk = (const char*)(ws + PACKED_OFF);

  // ---- nhn -> LDS (takes it out of the loop's vmcnt domain)
  const float nv0 = ws[NHN_OFF + tid];
  const float nv1 = ws[NHN_OFF + 512 + tid];

  // ---- x: direct global->reg (no LDS), per instr two 128B segments
  short8 xh[4], xl[4];
  float xx;
  {
    float vv[4][8];
    const float* xb = xin + ((size_t)(bb * 64 + half * 8)) * 4096 + hw0 + w * 32 + col;
#pragma unroll
    for (int kf = 0; kf < 4; ++kf)
#pragma unroll
      for (int j = 0; j < 8; ++j)
        vv[kf][j] = xb[((size_t)(kf * 16 + j)) * 4096];
    float s = 0.f;
#pragma unroll
    for (int kf = 0; kf < 4; ++kf)
#pragma unroll
      for (int j = 0; j < 8; ++j) {
        const float v = vv[kf][j];
        float rest, dump;
        xh[kf][j] = (short)bf16_rne(v, rest);
        xl[kf][j] = (short)bf16_rne(rest, dump);
        s += v * v;
      }
    s += __shfl_xor(s, 32);  // lanes l, l^32: same q, complementary dims
    xx = s;
  }
  nhl[tid] = nv0;
  nhl[512 + tid] = nv1;
  asm volatile("s_waitcnt lgkmcnt(0)" ::: "memory");  // nhn ds_writes done
  asm volatile("s_waitcnt vmcnt(0)" ::: "memory");    // clean vmcnt base

  // best[r]: score with low 5 mantissa bits = (31 - (ch*2+n)); fmax prefers
  // smaller code index on near-ties. <=2^-18 perturbation.
  float best[16];
#pragma unroll
  for (int r = 0; r < 16; ++r) best[r] = -3.4e38f;

  // stage chunk ch: 16KB over 8 waves -> 2 x 1KB GLL per wave
  auto stage = [&](int ch, int buf) {
    const char* src = pk + (size_t)ch * 16384 + w * 2048 + l * 16;
    char* dst = ring + buf * 16384 + w * 2048;
    GLL16(src, dst);
    GLL16(src + 1024, dst + 1024);
  };

  stage(0, 0);
  stage(1, 1);
  stage(2, 2);  // 6 outstanding per wave
  for (int i = 0; i < nch; ++i) {
    // wait for chunk i (its 2 GLLs are the oldest in flight; issued 3 periods
    // ago in steady state -> pre-satisfied)
    if (i < nch - 2) {
      asm volatile("s_waitcnt vmcnt(4)" ::: "memory");
    } else if (i == nch - 2) {
      asm volatile("s_waitcnt vmcnt(2)" ::: "memory");
    } else {
      asm volatile("s_waitcnt vmcnt(0)" ::: "memory");
    }
    __builtin_amdgcn_s_barrier();  // chunk i resident for ALL waves; i-1 consumed
    if (i + 3 < nch) stage(i + 3, (i + 3) & 3);  // overwrites buf[(i-1)&3]: safe
    const char* bufp = ring + (i & 3) * 16384;
    const int cb = col * 16;
    const float nh0 = nhl[i * 64 + col];        // ds_read: lgkmcnt, NOT vmcnt
    const float nh1 = nhl[i * 64 + 32 + col];
    f32x16 a0, a1;
#pragma unroll
    for (int r = 0; r < 16; ++r) { a0[r] = nh0; a1[r] = nh1; }
#pragma unroll
    for (int kf = 0; kf < 4; ++kf) {  // 4 sub-phases: 4 ds_read + 6 MFMA each
      const char* ph = bufp + (2 * kf + half) * 1024 + cb;
      const char* pl = bufp + (8 + 2 * kf + half) * 1024 + cb;
      const short8 bh0 = *(const short8*)(ph);
      const short8 bh1 = *(const short8*)(ph + 512);
      const short8 bl0 = *(const short8*)(pl);
      const short8 bl1 = *(const short8*)(pl + 512);
      asm volatile("s_waitcnt lgkmcnt(0)" ::: "memory");
      __builtin_amdgcn_sched_barrier(0);
      __builtin_amdgcn_s_setprio(1);
      a0 = __builtin_amdgcn_mfma_f32_32x32x16_bf16(xh[kf], bh0, a0, 0, 0, 0);
      a1 = __builtin_amdgcn_mfma_f32_32x32x16_bf16(xh[kf], bh1, a1, 0, 0, 0);
      a0 = __builtin_amdgcn_mfma_f32_32x32x16_bf16(xh[kf], bl0, a0, 0, 0, 0);
      a1 = __builtin_amdgcn_mfma_f32_32x32x16_bf16(xh[kf], bl1, a1, 0, 0, 0);
      a0 = __builtin_amdgcn_mfma_f32_32x32x16_bf16(xl[kf], bh0, a0, 0, 0, 0);
      a1 = __builtin_amdgcn_mfma_f32_32x32x16_bf16(xl[kf], bh1, a1, 0, 0, 0);
      __builtin_amdgcn_s_setprio(0);
    }
    const unsigned sid0 = (unsigned)(31 - 2 * i);
    const unsigned sid1 = (unsigned)(30 - 2 * i);
#pragma unroll
    for (int r = 0; r < 16; ++r) {
      const unsigned p0 = (__float_as_uint(a0[r]) & 0xFFFFFFE0u) | sid0;
      const unsigned p1 = (__float_as_uint(a1[r]) & 0xFFFFFFE0u) | sid1;
      best[r] = fmaxf(best[r], fmaxf(__uint_as_float(p0), __uint_as_float(p1)));
    }
  }

  // ---- cross-lane argmax reduce (within 32-lane half), first-index ties
  unsigned short* qidx = (unsigned short*)(ws + QIDX_OFF);
  float ls = 0.f;
#pragma unroll
  for (int r = 0; r < 16; ++r) {
    float v = best[r];
    int idx = (int)(31u - (__float_as_uint(v) & 31u)) * 32 + col;
#pragma unroll
    for (int mk = 1; mk < 32; mk <<= 1) {
      const float ov = __shfl_xor(v, mk);
      const int oi = __shfl_xor(idx, mk);
      if (ov > v || (ov == v && oi < idx)) { v = ov; idx = oi; }
    }
    const int row = (r & 3) + 8 * (r >> 2) + 4 * half;  // C layout row
    if (col == row) {
      const float vc = __uint_as_float(__float_as_uint(v) & 0xFFFFFFE0u);
      ls += xx - 2.0f * vc;  // ||x||^2 - 2(x.c* - 0.5||c*||^2) = ||x-c*||^2
      qidx[blk * 256 + w * 32 + row] = (unsigned short)idx;
    }
  }
#pragma unroll
  for (int mk = 1; mk < 64; mk <<= 1) ls += __shfl_xor(ls, mk);
  if (l == 0) atomicAdd(&ws[LOSS_OFF + (blk & (NPART - 1))], ls);
}

__global__ __launch_bounds__(256) void vq_out(
    const float* __restrict__ cb0, const float* __restrict__ cb1,
    float* __restrict__ out, float* __restrict__ ws) {
  const int tid = threadIdx.x;
  const int blk = blockIdx.x;  // 512 blocks x 256 q
  const int bb = blk >> 4;
  const int hw0 = (blk & 15) << 8;
  const int q = bb * 4096 + hw0 + tid;
  const int ci = (int)((const unsigned short*)(ws + QIDX_OFF))[q];
  atomicAdd(ws + PART_OFF + (size_t)(blk & (NPART - 1)) * 1024 + ci, 1.0f);
  const float* crow = (ci < 512) ? (cb0 + (size_t)ci * 64) : (cb1 + (size_t)(ci - 512) * 64);
  float* ob = out + (((size_t)(bb * 64)) << 12) + hw0 + tid;
#pragma unroll
  for (int d4 = 0; d4 < 16; ++d4) {
    const float4 f = *(const float4*)(crow + d4 * 4);
    ob[((size_t)(d4 * 4 + 0)) << 12] = f.x;
    ob[((size_t)(d4 * 4 + 1)) << 12] = f.y;
    ob[((size_t)(d4 * 4 + 2)) << 12] = f.z;
    ob[((size_t)(d4 * 4 + 3)) << 12] = f.w;
  }
}

__global__ void vq_final(const float* __restrict__ ws, float* __restrict__ out) {
  __shared__ float sred[256];
  const int t = threadIdx.x;
  float h = 0.f;
#pragma unroll
  for (int i = t; i < 1024; i += 256) {
    float s = 0.f;
#pragma unroll
    for (int p = 0; p < NPART; ++p) s += ws[PART_OFF + p * 1024 + i];
    const float avg = s * (1.0f / 131072.0f);
    h += avg * logf(avg + 1e-10f);
  }
  sred[t] = h;
  __syncthreads();
  for (int s2 = 128; s2 > 0; s2 >>= 1) {
    if (t < s2) sred[t] += sred[t + s2];
    __syncthreads();
  }
  if (t == 0) {
    float lsum = 0.f;
#pragma unroll
    for (int p = 0; p < NPART; ++p) lsum += ws[LOSS_OFF + p];
    out[8388608] = 1.25f * lsum * (1.0f / 8388608.0f);
    out[8388609] = expf(-sred[0]);
  }
}

extern "C" void kernel_launch(void* const* d_in, const int* in_sizes, int n_in,
                              void* d_out, int out_size, void* d_ws, size_t ws_size,
                              hipStream_t stream) {
  (void)in_sizes; (void)n_in; (void)out_size; (void)ws_size;
  const float* xin = (const float*)d_in[0];
  const float* cb0 = (const float*)d_in[1];
  const float* cb1 = (const float*)d_in[2];
  const int* idxp = (const int*)d_in[3];
  float* out = (float*)d_out;
  float* ws = (float*)d_ws;

  vq_pack<<<4, 256, 0, stream>>>(cb0, cb1, ws);
  vq_dist<<<512, 512, 0, stream>>>(xin, idxp, ws);
  vq_out<<<512, 256, 0, stream>>>(cb0, cb1, out, ws);
  vq_final<<<1, 256, 0, stream>>>(ws, out);
}

// Round 12
// 97.986 us; speedup vs baseline: 1.1736x; 1.0361x over previous
//
#include <hip/hip_runtime.h>

// VQ-VAE vector quantization via bf16-split MFMA (x=xh+xl, c=ch+cl; score =
// xh.ch + xh.cl + xl.ch - 0.5||c||^2, err ~2^-18 relative).
// Round 12: M=64 per wave. Floor math (corrected): matrix pipe is per-SIMD ->
// MFMA floor 5.1us; the dominant fixed cost was LDS ds_read_b128 traffic
// (scales with waves x chunks). M=64/wave doubles MFMA per B-byte and 1
// block/CU (8 waves x 512 thr, 256 blocks) halves per-CU LDS reads/chunk to
// 128. Ring-4 + depth-3 counted vmcnt + nhn-in-LDS kept from rounds 10/11.
// ws layout (floats):
//   [0..31]         loss partials
//   [1024..2047]    nhn = -0.5||c||^2
//   [2048..34815]   hist partials 32 x 1024
//   [34816..100351] packed codes: 16 chunks x 4096 floats (16KB):
//                   [16 granules][64 codes][16B]; g<8: hi dims 8g.., g>=8: lo
//   [102400..167935] qidx as ushort[131072]

typedef __attribute__((ext_vector_type(8))) short short8;
typedef __attribute__((ext_vector_type(16))) float f32x16;

#define LOSS_OFF 0
#define NHN_OFF 1024
#define PART_OFF 2048
#define PACKED_OFF 34816
#define QIDX_OFF 102400
#define NPART 32

#define GLL16(gsrc, ldst)                                                      \
  __builtin_amdgcn_global_load_lds(                                            \
      (const __attribute__((address_space(1))) void*)(gsrc),                   \
      (__attribute__((address_space(3))) void*)(ldst), 16, 0, 0)

__device__ __forceinline__ unsigned short bf16_rne(float v, float& rest) {
  const unsigned u = __float_as_uint(v);
  const unsigned r = u + 0x7fffu + ((u >> 16) & 1u);
  const unsigned short h = (unsigned short)(r >> 16);
  rest = v - __uint_as_float((unsigned)h << 16);
  return h;
}

__global__ void vq_pack(const float* __restrict__ cb0, const float* __restrict__ cb1,
                        float* __restrict__ ws) {
  const int c = blockIdx.x * 256 + threadIdx.x;  // 0..1023
  if (c < NPART) ws[LOSS_OFF + c] = 0.0f;
#pragma unroll
  for (int p = 0; p < NPART; ++p) ws[PART_OFF + p * 1024 + c] = 0.0f;
  const float* row = (c < 512) ? (cb0 + (size_t)c * 64) : (cb1 + (size_t)(c - 512) * 64);
  float v[64];
  float nrm = 0.f;
#pragma unroll
  for (int d = 0; d < 64; d += 4) {
    const float4 f = *(const float4*)(row + d);
    v[d] = f.x; v[d + 1] = f.y; v[d + 2] = f.z; v[d + 3] = f.w;
    nrm += f.x * f.x + f.y * f.y + f.z * f.z + f.w * f.w;
  }
  ws[NHN_OFF + c] = -0.5f * nrm;
  unsigned short hi[64], lo[64];
#pragma unroll
  for (int d = 0; d < 64; ++d) {
    float rest, dump;
    hi[d] = bf16_rne(v[d], rest);
    lo[d] = bf16_rne(rest, dump);
  }
  float* base = ws + PACKED_OFF + (size_t)(c >> 6) * 4096 + (c & 63) * 4;
#pragma unroll
  for (int g = 0; g < 16; ++g) {
    short8 gr;
#pragma unroll
    for (int e = 0; e < 8; ++e)
      gr[e] = (short)((g < 8) ? hi[g * 8 + e] : lo[(g - 8) * 8 + e]);
    *(short8*)(base + g * 256) = gr;
  }
}

__global__ __launch_bounds__(512, 2) void vq_dist(
    const float* __restrict__ xin, const int* __restrict__ idxp,
    float* __restrict__ ws) {
  __shared__ char smem[69632];  // 4 x 16KB ring + 4KB nhn
  char* ring = smem;
  float* nhl = (float*)(smem + 65536);
  const int tid = threadIdx.x;
  const int w = tid >> 6;      // wave 0..7, owns q rows w*64..+63
  const int l = tid & 63;
  const int half = l >> 5;
  const int col = l & 31;
  const int blk = blockIdx.x;  // 256 blocks x 512 q
  const int bb = blk >> 3;
  const int hw0 = (blk & 7) << 9;
  const int nch = (*idxp == 0) ? 8 : 16;
  const char* pk = (const char*)(ws + PACKED_OFF);

  // ---- nhn -> LDS (out of the K-loop's vmcnt domain)
  const float nv0 = ws[NHN_OFF + tid];
  const float nv1 = ws[NHN_OFF + 512 + tid];

  // ---- x: direct global->reg, 2 M-tiles (q = w*64 + m*32 + col)
  short8 xh[2][4], xl[2][4];
  float xx[2];
#pragma unroll
  for (int m = 0; m < 2; ++m) {
    float vv[4][8];
    const float* xb =
        xin + ((size_t)(bb * 64 + half * 8)) * 4096 + hw0 + w * 64 + m * 32 + col;
#pragma unroll
    for (int kf = 0; kf < 4; ++kf)
#pragma unroll
      for (int j = 0; j < 8; ++j)
        vv[kf][j] = xb[((size_t)(kf * 16 + j)) * 4096];
    float s = 0.f;
#pragma unroll
    for (int kf = 0; kf < 4; ++kf)
#pragma unroll
      for (int j = 0; j < 8; ++j) {
        const float v = vv[kf][j];
        float rest, dump;
        xh[m][kf][j] = (short)bf16_rne(v, rest);
        xl[m][kf][j] = (short)bf16_rne(rest, dump);
        s += v * v;
      }
    s += __shfl_xor(s, 32);  // lanes l, l^32: same q, complementary dims
    xx[m] = s;
  }
  nhl[tid] = nv0;
  nhl[512 + tid] = nv1;
  asm volatile("s_waitcnt lgkmcnt(0)" ::: "memory");  // nhn ds_writes done
  asm volatile("s_waitcnt vmcnt(0)" ::: "memory");    // clean vmcnt base

  // best[m][r]: score with low 5 mantissa bits = (31 - (ch*2+n)); fmax
  // prefers smaller code index on near-ties. <=2^-18 perturbation.
  float best[2][16];
#pragma unroll
  for (int m = 0; m < 2; ++m)
#pragma unroll
    for (int r = 0; r < 16; ++r) best[m][r] = -3.4e38f;

  // stage chunk ch: 16KB over 8 waves -> 2 x 1KB GLL per wave
  auto stage = [&](int ch, int buf) {
    const char* src = pk + (size_t)ch * 16384 + w * 2048 + l * 16;
    char* dst = ring + buf * 16384 + w * 2048;
    GLL16(src, dst);
    GLL16(src + 1024, dst + 1024);
  };

  stage(0, 0);
  stage(1, 1);
  stage(2, 2);  // 6 outstanding per wave
  for (int i = 0; i < nch; ++i) {
    // chunk i's 2 GLLs are the oldest in flight (issued 3 periods back)
    if (i < nch - 2) {
      asm volatile("s_waitcnt vmcnt(4)" ::: "memory");
    } else if (i == nch - 2) {
      asm volatile("s_waitcnt vmcnt(2)" ::: "memory");
    } else {
      asm volatile("s_waitcnt vmcnt(0)" ::: "memory");
    }
    __builtin_amdgcn_s_barrier();  // chunk i resident; chunk i-1 consumed
    if (i + 3 < nch) stage(i + 3, (i + 3) & 3);  // refills buf[(i-1)&3]: safe
    const char* bufp = ring + (i & 3) * 16384;
    const int cb = col * 16;
    const float nh0 = nhl[i * 64 + col];        // ds_read (lgkmcnt domain)
    const float nh1 = nhl[i * 64 + 32 + col];
    f32x16 a00, a01, a10, a11;
#pragma unroll
    for (int r = 0; r < 16; ++r) {
      a00[r] = nh0; a01[r] = nh1; a10[r] = nh0; a11[r] = nh1;
    }
#pragma unroll
    for (int kf = 0; kf < 4; ++kf) {  // 4 sub-phases: 4 ds_read + 12 MFMA
      const char* ph = bufp + (2 * kf + half) * 1024 + cb;
      const char* pl = bufp + (8 + 2 * kf + half) * 1024 + cb;
      const short8 bh0 = *(const short8*)(ph);
      const short8 bh1 = *(const short8*)(ph + 512);
      const short8 bl0 = *(const short8*)(pl);
      const short8 bl1 = *(const short8*)(pl + 512);
      asm volatile("s_waitcnt lgkmcnt(0)" ::: "memory");
      __builtin_amdgcn_sched_barrier(0);
      __builtin_amdgcn_s_setprio(1);
      a00 = __builtin_amdgcn_mfma_f32_32x32x16_bf16(xh[0][kf], bh0, a00, 0, 0, 0);
      a01 = __builtin_amdgcn_mfma_f32_32x32x16_bf16(xh[0][kf], bh1, a01, 0, 0, 0);
      a10 = __builtin_amdgcn_mfma_f32_32x32x16_bf16(xh[1][kf], bh0, a10, 0, 0, 0);
      a11 = __builtin_amdgcn_mfma_f32_32x32x16_bf16(xh[1][kf], bh1, a11, 0, 0, 0);
      a00 = __builtin_amdgcn_mfma_f32_32x32x16_bf16(xh[0][kf], bl0, a00, 0, 0, 0);
      a01 = __builtin_amdgcn_mfma_f32_32x32x16_bf16(xh[0][kf], bl1, a01, 0, 0, 0);
      a10 = __builtin_amdgcn_mfma_f32_32x32x16_bf16(xh[1][kf], bl0, a10, 0, 0, 0);
      a11 = __builtin_amdgcn_mfma_f32_32x32x16_bf16(xh[1][kf], bl1, a11, 0, 0, 0);
      a00 = __builtin_amdgcn_mfma_f32_32x32x16_bf16(xl[0][kf], bh0, a00, 0, 0, 0);
      a01 = __builtin_amdgcn_mfma_f32_32x32x16_bf16(xl[0][kf], bh1, a01, 0, 0, 0);
      a10 = __builtin_amdgcn_mfma_f32_32x32x16_bf16(xl[1][kf], bh0, a10, 0, 0, 0);
      a11 = __builtin_amdgcn_mfma_f32_32x32x16_bf16(xl[1][kf], bh1, a11, 0, 0, 0);
      __builtin_amdgcn_s_setprio(0);
    }
    const unsigned sid0 = (unsigned)(31 - 2 * i);
    const unsigned sid1 = (unsigned)(30 - 2 * i);
#pragma unroll
    for (int r = 0; r < 16; ++r) {
      const unsigned p00 = (__float_as_uint(a00[r]) & 0xFFFFFFE0u) | sid0;
      const unsigned p01 = (__float_as_uint(a01[r]) & 0xFFFFFFE0u) | sid1;
      best[0][r] = fmaxf(best[0][r], fmaxf(__uint_as_float(p00), __uint_as_float(p01)));
      const unsigned p10 = (__float_as_uint(a10[r]) & 0xFFFFFFE0u) | sid0;
      const unsigned p11 = (__float_as_uint(a11[r]) & 0xFFFFFFE0u) | sid1;
      best[1][r] = fmaxf(best[1][r], fmaxf(__uint_as_float(p10), __uint_as_float(p11)));
    }
  }

  // ---- cross-lane argmax reduce (within 32-lane half), first-index ties
  unsigned short* qidx = (unsigned short*)(ws + QIDX_OFF);
  float ls = 0.f;
#pragma unroll
  for (int m = 0; m < 2; ++m) {
#pragma unroll
    for (int r = 0; r < 16; ++r) {
      float v = best[m][r];
      int idx = (int)(31u - (__float_as_uint(v) & 31u)) * 32 + col;
#pragma unroll
      for (int mk = 1; mk < 32; mk <<= 1) {
        const float ov = __shfl_xor(v, mk);
        const int oi = __shfl_xor(idx, mk);
        if (ov > v || (ov == v && oi < idx)) { v = ov; idx = oi; }
      }
      const int row = (r & 3) + 8 * (r >> 2) + 4 * half;  // C layout row
      if (col == row) {
        const float vc = __uint_as_float(__float_as_uint(v) & 0xFFFFFFE0u);
        ls += xx[m] - 2.0f * vc;  // ||x||^2 - 2(x.c* - 0.5||c*||^2)
        qidx[blk * 512 + w * 64 + m * 32 + row] = (unsigned short)idx;
      }
    }
  }
#pragma unroll
  for (int mk = 1; mk < 64; mk <<= 1) ls += __shfl_xor(ls, mk);
  if (l == 0) atomicAdd(&ws[LOSS_OFF + (blk & (NPART - 1))], ls);
}

__global__ __launch_bounds__(256) void vq_out(
    const float* __restrict__ cb0, const float* __restrict__ cb1,
    float* __restrict__ out, float* __restrict__ ws) {
  const int tid = threadIdx.x;
  const int blk = blockIdx.x;  // 512 blocks x 256 q
  const int bb = blk >> 4;
  const int hw0 = (blk & 15) << 8;
  const int q = bb * 4096 + hw0 + tid;
  const int ci = (int)((const unsigned short*)(ws + QIDX_OFF))[q];
  atomicAdd(ws + PART_OFF + (size_t)(blk & (NPART - 1)) * 1024 + ci, 1.0f);
  const float* crow = (ci < 512) ? (cb0 + (size_t)ci * 64) : (cb1 + (size_t)(ci - 512) * 64);
  float* ob = out + (((size_t)(bb * 64)) << 12) + hw0 + tid;
#pragma unroll
  for (int d4 = 0; d4 < 16; ++d4) {
    const float4 f = *(const float4*)(crow + d4 * 4);
    ob[((size_t)(d4 * 4 + 0)) << 12] = f.x;
    ob[((size_t)(d4 * 4 + 1)) << 12] = f.y;
    ob[((size_t)(d4 * 4 + 2)) << 12] = f.z;
    ob[((size_t)(d4 * 4 + 3)) << 12] = f.w;
  }
}

__global__ void vq_final(const float* __restrict__ ws, float* __restrict__ out) {
  __shared__ float sred[256];
  const int t = threadIdx.x;
  float h = 0.f;
#pragma unroll
  for (int i = t; i < 1024; i += 256) {
    float s = 0.f;
#pragma unroll
    for (int p = 0; p < NPART; ++p) s += ws[PART_OFF + p * 1024 + i];
    const float avg = s * (1.0f / 131072.0f);
    h += avg * logf(avg + 1e-10f);
  }
  sred[t] = h;
  __syncthreads();
  for (int s2 = 128; s2 > 0; s2 >>= 1) {
    if (t < s2) sred[t] += sred[t + s2];
    __syncthreads();
  }
  if (t == 0) {
    float lsum = 0.f;
#pragma unroll
    for (int p = 0; p < NPART; ++p) lsum += ws[LOSS_OFF + p];
    out[8388608] = 1.25f * lsum * (1.0f / 8388608.0f);
    out[8388609] = expf(-sred[0]);
  }
}

extern "C" void kernel_launch(void* const* d_in, const int* in_sizes, int n_in,
                              void* d_out, int out_size, void* d_ws, size_t ws_size,
                              hipStream_t stream) {
  (void)in_sizes; (void)n_in; (void)out_size; (void)ws_size;
  const float* xin = (const float*)d_in[0];
  const float* cb0 = (const float*)d_in[1];
  const float* cb1 = (const float*)d_in[2];
  const int* idxp = (const int*)d_in[3];
  float* out = (float*)d_out;
  float* ws = (float*)d_ws;

  vq_pack<<<4, 256, 0, stream>>>(cb0, cb1, ws);
  vq_dist<<<256, 512, 0, stream>>>(xin, idxp, ws);
  vq_out<<<512, 256, 0, stream>>>(cb0, cb1, out, ws);
  vq_final<<<1, 256, 0, stream>>>(ws, out);
}